// Round 16
// baseline (795.965 us; speedup 1.0000x reference)
//
#include <hip/hip_runtime.h>

// ---------------------------------------------------------------------------
// FusedSparseLMHead: weighted-mean CE over h @ W^T without materializing logits.
//   h: [4096, 2048] f32, W: [65536, 2048] f32, labels: [4096] int, w: [4096] f32
// Round 16: i8 GEMM, 128x256 tile (tokens x vocab), BK=64 B, 48 KB LDS,
//   acc 64 VGPR -> __launch_bounds__(512,4) = 4 waves/SIMD = 2 blocks/CU
//   (m114 cross-block overlap hides the per-K-tile vmcnt(0)+barrier stall --
//   the residue 3 prior rounds could not schedule away at 1 block/CU).
//   NO swizzle anywhere: 64-B rows + 16-row frags + contiguous-k i8 make
//   lane->granule a perfect bijection on both stage-write and frag-read
//   (identical to m134's conflict-free baseline; r15 measured 0).
//   Schedule/K-tile: {stage(t+1) 3 gloads; 8 ds_read_b128; 16 MFMA;
//   vmcnt(0); bar} -- m97's minimal proven loop.
//   Numerics (r15-verified): h*16 rne clamp127, W*1024; i32 accum exact;
//   epilogue /16384 exact; label logit exact fp32.
// ---------------------------------------------------------------------------

typedef __attribute__((ext_vector_type(4)))  float f32x4;
typedef __attribute__((ext_vector_type(8)))  float f32x8;
typedef __attribute__((ext_vector_type(4)))  int   i32x4;

#define N_TOK 4096
#define DIM   2048          // i8 bytes per row
#define VOCAB 65536
#define BM    128           // token rows per block
#define BN    256           // vocab rows per block
#define BK    64            // i8 elements per K-tile
#define NT    (DIM / BK)    // 32 K-tiles
#define NCH   (VOCAB / BN)  // 256 vocab chunks
#define NTB   (N_TOK / BM)  // 32 token blocks

__device__ __forceinline__ void gload_lds16(const void* g, void* l) {
    __builtin_amdgcn_global_load_lds(
        (const __attribute__((address_space(1))) void*)g,
        (__attribute__((address_space(3))) void*)l, 16, 0, 0);
}

__device__ __forceinline__ void bar() {
    asm volatile("" ::: "memory");
    __builtin_amdgcn_s_barrier();
    asm volatile("" ::: "memory");
}

// ------------------------------------------------- convert f32 -> int8 -----
__global__ __launch_bounds__(256) void convert_f32_i8(
    const float* __restrict__ src, signed char* __restrict__ dst,
    long n, float scale)
{
    long i = ((long)blockIdx.x * 256 + threadIdx.x) * 8;
    if (i + 8 > n) return;
    f32x8 v = *(const f32x8*)(src + i);
    signed char o[8];
    #pragma unroll
    for (int j = 0; j < 8; ++j) {
        float x = v[j] * scale;
        x = fminf(fmaxf(x, -127.0f), 127.0f);
        o[j] = (signed char)__float2int_rn(x);
    }
    *(uint2*)(dst + i) = *(const uint2*)o;   // plain contiguous, coalesced
}

// --------------- i8 16x16x64, 128x256 tile, 2-blocks/CU GEMM+LSE -----------
__global__ __launch_bounds__(512, 4) void gemm_lse(
    const signed char* __restrict__ h8,      // [4096][2048] i8 (x16)
    const signed char* __restrict__ W8,      // [seg_rows][2048] i8 (x1024)
    float* __restrict__ part_m, float* __restrict__ part_s, int chunk0)
{
    __shared__ unsigned char A_lds[2][8192];    // [par][128r x 64B] 16 KB
    __shared__ unsigned char B_lds[2][16384];   // [par][256r x 64B] 32 KB

    const int tid  = threadIdx.x;
    const int lane = tid & 63;
    const int w    = tid >> 6;       // wave 0..7
    const int wmr  = w >> 2;         // 0..1 : token half (64 rows)
    const int wnc  = w & 3;          // 0..3 : vocab quarter (64 cols)

    // bijective XCD-aware remap, token-fastest decode: the 32 consecutive wg
    // sharing one 512 KB B-panel land on ONE XCD -> panel stays L2-hot.
    const int nwg  = gridDim.x;
    const int orig = blockIdx.x;
    const int q8 = nwg >> 3, r8 = nwg & 7;
    const int xcd = orig & 7;
    const int wg  = (xcd < r8 ? xcd * (q8 + 1) : r8 * (q8 + 1) + (xcd - r8) * q8)
                    + (orig >> 3);
    const int tok_blk = wg & (NTB - 1);
    const int voc_blk = wg >> 5;                 // NTB == 32

    const long arow0 = (long)tok_blk * BM;
    const signed char* Ab = h8 + arow0 * DIM;
    const signed char* Bb = W8 + (long)voc_blk * BN * DIM;

    i32x4 acc[4][4];
    #pragma unroll
    for (int i = 0; i < 4; ++i)
        #pragma unroll
        for (int j = 0; j < 4; ++j)
            acc[i][j] = (i32x4){0, 0, 0, 0};

    // ---- staging: NO swizzle. A tile 128r x 4 chunks = 512 chunks (1/thr);
    // B tile 1024 chunks (2 sweeps). Thread tid -> chunk tid (+ j*512):
    // r = idx>>2, c = idx&3; linear source AND linear dest (lane*16 by HW).
    const long soff = (long)(tid >> 2) * DIM + (tid & 3) * 16;
    const int  sdb  = w * 1024;     // wave-uniform dest base (bytes)

#define SW_A(t, PD)                                                           \
    gload_lds16(Ab + (t) * BK + soff, (char*)&A_lds[PD][0] + sdb);
#define SW_B(t, PD, j)                                                        \
    gload_lds16(Bb + (t) * BK + soff + (long)(j) * 128 * DIM,                 \
                (char*)&B_lds[PD][0] + sdb + (j) * 8192);

    // ---- fragment reads: 16-row frag, row = base + (lane&15), k-granule
    // c = lane>>4. granule(l) = (l&15)*4 + (l>>4): 64 DISTINCT granules =
    // a clean 1024-B sweep (m134 conflict-free shape). One b128 = one operand.
    const int rbase = (lane & 15) * 64 + (lane >> 4) * 16;

#define KTILE(CUR, NXT, t)                                                    \
    {                                                                         \
        if ((t) + 1 < NT) {                                                   \
            SW_A((t) + 1, NXT)                                                \
            SW_B((t) + 1, NXT, 0)                                             \
            SW_B((t) + 1, NXT, 1)                                             \
        }                                                                     \
        const char* Ah = (const char*)&A_lds[CUR][0] + wmr * 4096 + rbase;    \
        const char* Bh = (const char*)&B_lds[CUR][0] + wnc * 4096 + rbase;    \
        i32x4 aR[4], bR[4];                                                   \
        _Pragma("unroll")                                                     \
        for (int m = 0; m < 4; ++m) aR[m] = *(const i32x4*)(Ah + m * 1024);   \
        _Pragma("unroll")                                                     \
        for (int n = 0; n < 4; ++n) bR[n] = *(const i32x4*)(Bh + n * 1024);   \
        __builtin_amdgcn_s_setprio(1);                                        \
        _Pragma("unroll")                                                     \
        for (int m = 0; m < 4; ++m)                                           \
            _Pragma("unroll")                                                 \
            for (int n = 0; n < 4; ++n)                                       \
                acc[m][n] = __builtin_amdgcn_mfma_i32_16x16x64_i8(            \
                    aR[m], bR[n], acc[m][n], 0, 0, 0);                        \
        __builtin_amdgcn_s_setprio(0);                                        \
        asm volatile("s_waitcnt vmcnt(0)" ::: "memory");                      \
        bar();                                                                \
    }

    // prologue: tile 0 -> buf 0
    SW_A(0, 0) SW_B(0, 0, 0) SW_B(0, 0, 1)
    asm volatile("s_waitcnt vmcnt(0)" ::: "memory");
    bar();

    for (int t = 0; t < NT; t += 2) {
        KTILE(0, 1, t)
        KTILE(1, 0, t + 1)
    }
#undef KTILE
#undef SW_A
#undef SW_B

    // ---- epilogue: exact dequant (1/16384), per-token (max, sumexp) -------
    // C frag (verified): row = wmr*64 + m*16 + (lane>>4)*4 + r,
    // col = wnc*64 + n*16 + (lane&15). 16-wide shfl only.
    const float INV = 1.0f / 16384.0f;
    float* red_m = (float*)&A_lds[0][0];          // 2 KB
    float* red_s = ((float*)&A_lds[0][0]) + 512;  // 2 KB
    #pragma unroll
    for (int m = 0; m < 4; ++m) {
        #pragma unroll
        for (int r = 0; r < 4; ++r) {
            float v0 = (float)acc[m][0][r] * INV;
            float v1 = (float)acc[m][1][r] * INV;
            float v2 = (float)acc[m][2][r] * INV;
            float v3 = (float)acc[m][3][r] * INV;
            float mx = fmaxf(fmaxf(v0, v1), fmaxf(v2, v3));
            #pragma unroll
            for (int msk = 1; msk < 16; msk <<= 1)
                mx = fmaxf(mx, __shfl_xor(mx, msk, 64));
            float se = __expf(v0 - mx) + __expf(v1 - mx) +
                       __expf(v2 - mx) + __expf(v3 - mx);
            #pragma unroll
            for (int msk = 1; msk < 16; msk <<= 1)
                se += __shfl_xor(se, msk, 64);
            if ((lane & 15) == 0) {
                const int row = wmr * 64 + m * 16 + (lane >> 4) * 4 + r;
                red_m[row * 4 + wnc] = mx;
                red_s[row * 4 + wnc] = se;
            }
        }
    }
    __syncthreads();
    if (tid < BM) {
        float M = red_m[tid * 4], S = red_s[tid * 4];
        #pragma unroll
        for (int j = 1; j < 4; ++j) {
            const float m2 = red_m[tid * 4 + j], s2 = red_s[tid * 4 + j];
            const float Mn = fmaxf(M, m2);
            S = S * __expf(M - Mn) + s2 * __expf(m2 - Mn);
            M = Mn;
        }
        part_m[(arow0 + tid) * NCH + chunk0 + voc_blk] = M;
        part_s[(arow0 + tid) * NCH + chunk0 + voc_blk] = S;
    }
}

// ------------------------------------------------------- exact label dot ----
__global__ __launch_bounds__(256) void label_dot(
    const float* __restrict__ h, const float* __restrict__ W,
    const void* __restrict__ labels, float* __restrict__ lab_logit)
{
    bool is64 = true;
    #pragma unroll
    for (int i = 0; i < 8; ++i) {
        long long v = ((const long long*)labels)[i];
        if (v < 0 || v >= VOCAB) is64 = false;
    }
    const int t = blockIdx.x;
    const int lab = is64 ? (int)((const long long*)labels)[t]
                         : ((const int*)labels)[t];
    const float4* hp = (const float4*)(h + (long)t * DIM);
    const float4* wp = (const float4*)(W + (long)lab * DIM);
    float s = 0.f;
    #pragma unroll
    for (int j = 0; j < 2; ++j) {
        const float4 a = hp[threadIdx.x + j * 256];
        const float4 b = wp[threadIdx.x + j * 256];
        s += a.x * b.x + a.y * b.y + a.z * b.z + a.w * b.w;
    }
    #pragma unroll
    for (int msk = 1; msk < 64; msk <<= 1) s += __shfl_xor(s, msk, 64);
    __shared__ float ps[4];
    if ((threadIdx.x & 63) == 0) ps[threadIdx.x >> 6] = s;
    __syncthreads();
    if (threadIdx.x == 0) lab_logit[t] = ps[0] + ps[1] + ps[2] + ps[3];
}

// ---------------------------------------------------- per-token LSE merge ---
__global__ __launch_bounds__(256) void finalize_nll(
    const float* __restrict__ part_m, const float* __restrict__ part_s,
    const float* __restrict__ lab_logit, const float* __restrict__ wts,
    float* __restrict__ wnll)
{
    const int t    = blockIdx.x * 4 + (threadIdx.x >> 6);  // one wave / token
    const int lane = threadIdx.x & 63;
    float m = -3.4e38f, s = 0.f;
    #pragma unroll
    for (int j = 0; j < 4; ++j) {
        const int c = j * 64 + lane;
        const float pm = part_m[(long)t * NCH + c];
        const float ps = part_s[(long)t * NCH + c];
        const float M = fmaxf(m, pm);
        s = s * __expf(m - M) + ps * __expf(pm - M);
        m = M;
    }
    #pragma unroll
    for (int msk = 1; msk < 64; msk <<= 1) {
        const float om = __shfl_xor(m, msk, 64);
        const float os = __shfl_xor(s, msk, 64);
        const float M = fmaxf(m, om);
        s = s * __expf(m - M) + os * __expf(om - M);
        m = M;
    }
    if (lane == 0) {
        const float lse = m + logf(s);
        wnll[t] = wts[t] * (lse - lab_logit[t]);
    }
}

// -------------------------------------------------- deterministic reduce ----
__global__ __launch_bounds__(1024) void final_reduce(
    const float* __restrict__ wnll, const float* __restrict__ wts,
    float* __restrict__ out)
{
    float a = 0.f, b = 0.f;
    #pragma unroll
    for (int j = 0; j < 4; ++j) {
        const int i = threadIdx.x + j * 1024;
        a += wnll[i];
        b += wts[i];
    }
    #pragma unroll
    for (int msk = 1; msk < 64; msk <<= 1) {
        a += __shfl_xor(a, msk, 64);
        b += __shfl_xor(b, msk, 64);
    }
    __shared__ float pa[16], pb[16];
    if ((threadIdx.x & 63) == 0) {
        pa[threadIdx.x >> 6] = a;
        pb[threadIdx.x >> 6] = b;
    }
    __syncthreads();
    if (threadIdx.x == 0) {
        float A = 0.f, B = 0.f;
        #pragma unroll
        for (int i = 0; i < 16; ++i) { A += pa[i]; B += pb[i]; }
        out[0] = A / B;
    }
}

// ----------------------------------------------------------------- launch ---
extern "C" void kernel_launch(void* const* d_in, const int* in_sizes, int n_in,
                              void* d_out, int out_size, void* d_ws, size_t ws_size,
                              hipStream_t stream)
{
    const float* h      = (const float*)d_in[0];
    const void*  labels = d_in[1];
    const float* wts    = (const float*)d_in[2];
    const float* W      = (const float*)d_in[3];
    float* out = (float*)d_out;

    char* ws = (char*)d_ws;
    signed char*    h8        = (signed char*)(ws);                    //  8 MB
    float*          part_m    = (float*)(ws + (16u << 20));            //  4 MB
    float*          part_s    = (float*)(ws + (24u << 20));            //  4 MB
    float*          lab_logit = (float*)(ws + (32u << 20));            // 16 KB
    float*          wnll      = (float*)(ws + (32u << 20) + 16384);    // 16 KB
    signed char*    wseg      = (signed char*)(ws + (32u << 20) + 32768);
    const size_t base = (size_t)(32u << 20) + 32768;

    long segmax = 0;
    if (ws_size > base) segmax = (long)((ws_size - base) / (size_t)DIM);
    segmax &= ~255L;
    if (segmax > VOCAB) segmax = VOCAB;
    if (segmax < 256)   segmax = 256;   // require ws_size >= ~33.5 MB

    // 0) h -> i8 (x16)
    convert_f32_i8<<<(N_TOK * DIM) / (256 * 8), 256, 0, stream>>>(
        h, h8, (long)N_TOK * DIM, 16.0f);

    // 1) segmented W -> i8 (x1024) + fused GEMM/LSE partials
    for (long v0 = 0; v0 < VOCAB; v0 += segmax) {
        const long rows = (VOCAB - v0) < segmax ? (VOCAB - v0) : segmax;
        convert_f32_i8<<<(int)(rows * DIM / (256 * 8)), 256, 0, stream>>>(
            W + v0 * DIM, wseg, rows * (long)DIM, 1024.0f);
        const int nwg = (int)(rows / BN) * NTB;
        gemm_lse<<<nwg, 512, 0, stream>>>(h8, wseg, part_m, part_s,
                                          (int)(v0 / BN));
    }

    // 2) exact label logits (fp32)
    label_dot<<<N_TOK, 256, 0, stream>>>(h, W, labels, lab_logit);

    // 3) per-token LSE merge -> w*nll
    finalize_nll<<<N_TOK / 4, 256, 0, stream>>>(part_m, part_s, lab_logit,
                                                wts, wnll);

    // 4) weighted mean
    final_reduce<<<1, 1024, 0, stream>>>(wnll, wts, out);
}